// Round 3
// baseline (505.876 us; speedup 1.0000x reference)
//
#include <hip/hip_runtime.h>
#include <math.h>

typedef __attribute__((ext_vector_type(8))) __bf16 bf16x8;
typedef __attribute__((ext_vector_type(4))) __bf16 bf16x4;
typedef __attribute__((ext_vector_type(4))) float f32x4;

// max over the 16-lane group via DPP row rotations (VALU, not LDS pipe)
__device__ __forceinline__ float rowmax16(float x) {
    int xi = __builtin_bit_cast(int, x);
    float y;
    y = __builtin_bit_cast(float, __builtin_amdgcn_update_dpp(0, xi, 0x128, 0xf, 0xf, true)); // ror:8
    x = fmaxf(x, y); xi = __builtin_bit_cast(int, x);
    y = __builtin_bit_cast(float, __builtin_amdgcn_update_dpp(0, xi, 0x124, 0xf, 0xf, true)); // ror:4
    x = fmaxf(x, y); xi = __builtin_bit_cast(int, x);
    y = __builtin_bit_cast(float, __builtin_amdgcn_update_dpp(0, xi, 0x122, 0xf, 0xf, true)); // ror:2
    x = fmaxf(x, y); xi = __builtin_bit_cast(int, x);
    y = __builtin_bit_cast(float, __builtin_amdgcn_update_dpp(0, xi, 0x121, 0xf, 0xf, true)); // ror:1
    x = fmaxf(x, y);
    return x;
}

// ---------------------------------------------------------------------------
// prep: transpose + bf16-cast the three epilogue weight matrices.
// ---------------------------------------------------------------------------
__global__ void prep_kernel(const float* __restrict__ wlin,
                            const float* __restrict__ wu2,
                            const float* __restrict__ wsc,
                            __bf16* __restrict__ wlinT,
                            __bf16* __restrict__ wu2T,
                            __bf16* __restrict__ wscT)
{
    int i = blockIdx.x * 256 + threadIdx.x;
    if (i < 64 * 512) {
        int l = i >> 9, k = i & 511;
        wlinT[i] = (__bf16)wlin[k * 64 + l];
    } else if (i < 64 * 512 + 128 * 64) {
        int j = i - 64 * 512; int co = j >> 6, kk = j & 63;
        wu2T[j] = (__bf16)wu2[kk * 128 + co];
    } else if (i < 64 * 512 + 2 * 128 * 64) {
        int j = i - 64 * 512 - 128 * 64; int co = j >> 6, kk = j & 63;
        wscT[j] = (__bf16)wsc[kk * 128 + co];
    }
}

// ---------------------------------------------------------------------------
// Kernel A (MFMA): per block = 64 rows (4 waves x 16 rows), N % 64 == 0.
//   feats_x = leaky(df @ w1 + b1)  -> fx (bf16), via MFMA 16x16x32 (K=64, 2 kt)
//   guidance = feats_x @ wg + bg   -> gx (bf16), MFMA (K=32)
//   dfb = bf16(df)                 (for the shortcut max-pool gather)
// All LDS traffic is same-wave (C->A relayout); no __syncthreads at all.
// ---------------------------------------------------------------------------
__global__ __launch_bounds__(256) void feats_kernel(
    const float* __restrict__ df,
    const float* __restrict__ w1, const float* __restrict__ b1,
    const float* __restrict__ wg, const float* __restrict__ bg,
    __bf16* __restrict__ fx, __bf16* __restrict__ gx,
    __bf16* __restrict__ dfb, int N)
{
    __shared__ __bf16 sT[4][16][40];     // per-wave C<->A relayout buffer
    int t = threadIdx.x;
    int wv = t >> 6, ln = t & 63;
    int nn = ln & 15, quad = ln >> 4;

    // B-fragments in registers: lane holds B[k=quad*8+j][n=nn]
    bf16x8 bw1[2][2], bwg[2];
#pragma unroll
    for (int kt = 0; kt < 2; kt++)
#pragma unroll
        for (int nt = 0; nt < 2; nt++)
#pragma unroll
            for (int j = 0; j < 8; j++)
                bw1[kt][nt][j] = (__bf16)w1[(kt * 32 + quad * 8 + j) * 32 + nt * 16 + nn];
#pragma unroll
    for (int nt = 0; nt < 2; nt++)
#pragma unroll
        for (int j = 0; j < 8; j++)
            bwg[nt][j] = (__bf16)wg[(quad * 8 + j) * 32 + nt * 16 + nn];
    float bias1[2] = { b1[nn], b1[16 + nn] };
    float biasg[2] = { bg[nn], bg[16 + nn] };

    long row = (long)blockIdx.x * 64 + wv * 16 + nn;   // A-frag row (m = nn)
    const float4* drA = (const float4*)(df + row * 64 + quad * 8);
    const float4* drB = (const float4*)(df + row * 64 + 32 + quad * 8);
    float4 f0 = drA[0], f1 = drA[1];
    float4 f2 = drB[0], f3 = drB[1];
    bf16x8 a0, a1;
    a0[0] = (__bf16)f0.x; a0[1] = (__bf16)f0.y; a0[2] = (__bf16)f0.z; a0[3] = (__bf16)f0.w;
    a0[4] = (__bf16)f1.x; a0[5] = (__bf16)f1.y; a0[6] = (__bf16)f1.z; a0[7] = (__bf16)f1.w;
    a1[0] = (__bf16)f2.x; a1[1] = (__bf16)f2.y; a1[2] = (__bf16)f2.z; a1[3] = (__bf16)f2.w;
    a1[4] = (__bf16)f3.x; a1[5] = (__bf16)f3.y; a1[6] = (__bf16)f3.z; a1[7] = (__bf16)f3.w;
    // bf16 copy of df (coalesced 16B stores)
    *(bf16x8*)(dfb + row * 64 + quad * 8) = a0;
    *(bf16x8*)(dfb + row * 64 + 32 + quad * 8) = a1;

    // GEMM1: leaky(df @ w1 + b1)
#pragma unroll
    for (int nt = 0; nt < 2; nt++) {
        f32x4 acc = {0.f, 0.f, 0.f, 0.f};
        acc = __builtin_amdgcn_mfma_f32_16x16x32_bf16(a0, bw1[0][nt], acc, 0, 0, 0);
        acc = __builtin_amdgcn_mfma_f32_16x16x32_bf16(a1, bw1[1][nt], acc, 0, 0, 0);
#pragma unroll
        for (int r = 0; r < 4; r++) {
            float x = acc[r] + bias1[nt];
            x = x > 0.f ? x : 0.1f * x;
            sT[wv][quad * 4 + r][nt * 16 + nn] = (__bf16)x;   // C-layout: row=quad*4+r, col=nn
        }
    }
    // fx out (coalesced): lane -> (row ln>>2, 8-ch chunk ln&3)
    long rbase = (long)blockIdx.x * 64 + wv * 16;
    bf16x8 fxv = *(bf16x8*)(&sT[wv][ln >> 2][(ln & 3) * 8]);
    *(bf16x8*)(fx + (rbase + (ln >> 2)) * 32 + (ln & 3) * 8) = fxv;
    // A2-frag: A[m=nn][k=quad*8+j]
    bf16x8 a2 = *(bf16x8*)(&sT[wv][nn][quad * 8]);
    // GEMM2: feats_x @ wg + bg (no relu)
#pragma unroll
    for (int nt = 0; nt < 2; nt++) {
        f32x4 acc = {0.f, 0.f, 0.f, 0.f};
        acc = __builtin_amdgcn_mfma_f32_16x16x32_bf16(a2, bwg[nt], acc, 0, 0, 0);
#pragma unroll
        for (int r = 0; r < 4; r++)
            sT[wv][quad * 4 + r][nt * 16 + nn] = (__bf16)(acc[r] + biasg[nt]);
    }
    bf16x8 gxv = *(bf16x8*)(&sT[wv][ln >> 2][(ln & 3) * 8]);
    *(bf16x8*)(gx + (rbase + (ln >> 2)) * 32 + (ln & 3) * 8) = gxv;
}

// ---------------------------------------------------------------------------
// Kernel B: 16 sparse points / 256-thread block.
// phase1: per-(p,q) fp32 VALU pipeline -> nf(bf16), w3(bf16), sf(bf16) in LDS
// phase2: per-point nf^T @ w3 via zero-padded MFMA 16x16x32 (k=q, 16 real)
// phase3: MFMA: out64 = relu(agg @ wlin + blin)
// phase4: MFMA: out = leaky(out64 @ wu2 + sf @ wsc + b)
// ---------------------------------------------------------------------------
struct SmemU {
    union {
        struct { __bf16 nfb[16][16][40]; __bf16 w3b[16][16][24]; } a; // 32768 B
        __bf16 aggB[16][520];                                         // 16640 B
    };
};

__global__ __launch_bounds__(256, 4) void pcf_kernel(
    const float* __restrict__ vi, const int* __restrict__ nei,
    const __bf16* __restrict__ dfb,
    const __bf16* __restrict__ fx, const __bf16* __restrict__ gx,
    const float* __restrict__ wpe, const float* __restrict__ bpe,
    const float* __restrict__ wg1, const float* __restrict__ bg1,
    const float* __restrict__ wg2, const float* __restrict__ bg2,
    const float* __restrict__ wn1, const float* __restrict__ bn1,
    const float* __restrict__ wn2, const float* __restrict__ bn2,
    const float* __restrict__ wn3, const float* __restrict__ bn3,
    const __bf16* __restrict__ wlinT, const float* __restrict__ blin,
    const __bf16* __restrict__ wu2T, const float* __restrict__ bu2,
    const __bf16* __restrict__ wscT, const float* __restrict__ bsc,
    float* __restrict__ out, int M)
{
    __shared__ SmemU U;
    __shared__ __bf16 sO[16][72];
    __shared__ __bf16 sS[16][72];
    __shared__ int sInd[16][16];

    int t = threadIdx.x;
    int p = t >> 4, q = t & 15;
    long m = (long)blockIdx.x * 16 + p;
    bool okm = m < (long)M;
    int ind = okm ? nei[m * 16 + q] : 0;
    sInd[p][q] = ind;                 // consumed within the same wave only

    // ---------------- phase 1 ----------------
    float v[12];
    {
        const float4* v4 = (const float4*)(vi + (okm ? (m * 16 + q) * 12 : 0));
        float4 a = v4[0], b = v4[1], cc = v4[2];
        v[0] = a.x; v[1] = a.y; v[2] = a.z; v[3] = a.w;
        v[4] = b.x; v[5] = b.y; v[6] = b.z; v[7] = b.w;
        v[8] = cc.x; v[9] = cc.y; v[10] = cc.z; v[11] = cc.w;
    }
    float pe[32];
#pragma unroll
    for (int c = 0; c < 32; c++) {
        float a = bpe[c];
#pragma unroll
        for (int i = 0; i < 12; i++) a += v[i] * wpe[i * 32 + c];
        pe[c] = fmaxf(a, 0.f);
    }
    float gd[32];
    {
        const bf16x8* g8 = (const bf16x8*)(gx + (long)ind * 32);
        bf16x8 gA = g8[0], gB = g8[1], gC = g8[2], gD = g8[3];
#pragma unroll
        for (int j = 0; j < 8; j++) {
            gd[j] = (float)gA[j]; gd[8 + j] = (float)gB[j];
            gd[16 + j] = (float)gC[j]; gd[24 + j] = (float)gD[j];
        }
    }
    float s1[8];
#pragma unroll
    for (int j = 0; j < 8; j++) s1[j] = bg1[j];
#pragma unroll
    for (int i = 0; i < 64; i++) {
        float gi = (i < 32) ? gd[i] : pe[i - 32];
        float sub = gi - rowmax16(gi);
#pragma unroll
        for (int j = 0; j < 8; j++) s1[j] += sub * wg1[i * 8 + j];
    }
#pragma unroll
    for (int j = 0; j < 8; j++) s1[j] = fmaxf(s1[j], 0.f);
    float s2[8];
#pragma unroll
    for (int j = 0; j < 8; j++) {
        float a = bg2[j];
#pragma unroll
        for (int i = 0; i < 8; i++) a += s1[i] * wg2[i * 8 + j];
        s2[j] = 1.f / (1.f + __expf(-a));
    }
    float wa[8], wb[8];
#pragma unroll
    for (int j = 0; j < 8; j++) {
        float a = bn1[j];
#pragma unroll
        for (int i = 0; i < 12; i++) a += v[i] * wn1[i * 8 + j];
        wa[j] = fmaxf(a, 0.f);
    }
#pragma unroll
    for (int j = 0; j < 8; j++) {
        float a = bn2[j];
#pragma unroll
        for (int i = 0; i < 8; i++) a += wa[i] * wn2[i * 8 + j];
        wb[j] = fmaxf(a, 0.f);
    }
    {
        float w3v[16];
#pragma unroll
        for (int j = 0; j < 16; j++) {
            float a = bn3[j];
#pragma unroll
            for (int i = 0; i < 8; i++) a += wb[i] * wn3[i * 16 + j];
            w3v[j] = fmaxf(a, 0.f);
        }
        bf16x8 wlo, whi;
#pragma unroll
        for (int jj = 0; jj < 8; jj++) { wlo[jj] = (__bf16)w3v[jj]; whi[jj] = (__bf16)w3v[8 + jj]; }
        *(bf16x8*)(&U.a.w3b[p][q][0]) = wlo;
        *(bf16x8*)(&U.a.w3b[p][q][8]) = whi;
    }
    {
        const bf16x8* f8 = (const bf16x8*)(fx + (long)ind * 32);
#pragma unroll
        for (int g = 0; g < 4; g++) {
            bf16x8 f = f8[g];
            bf16x8 pk;
#pragma unroll
            for (int e = 0; e < 8; e++) {
                float s = s2[g * 2 + (e >> 2)];       // head = channel/4
                pk[e] = (__bf16)((float)f[e] * s);
            }
            *(bf16x8*)(&U.a.nfb[p][q][g * 8]) = pk;
        }
    }
    {
        float m0 = -1e30f, m1 = -1e30f, m2 = -1e30f, m3 = -1e30f;
#pragma unroll
        for (int kk = 0; kk < 16; kk++) {
            int ik = sInd[p][kk];
            bf16x4 d = *(const bf16x4*)(dfb + (long)ik * 64 + q * 4);
            m0 = fmaxf(m0, (float)d[0]); m1 = fmaxf(m1, (float)d[1]);
            m2 = fmaxf(m2, (float)d[2]); m3 = fmaxf(m3, (float)d[3]);
        }
        bf16x4 pk;
        pk[0] = (__bf16)m0; pk[1] = (__bf16)m1; pk[2] = (__bf16)m2; pk[3] = (__bf16)m3;
        *(bf16x4*)(&sS[p][q * 4]) = pk;
    }
    // NOTE: no barrier here — phase 2 only reads LDS written by the same wave
    // (wave wv owns p-groups 4wv..4wv+3 and reads exactly those).

    // ---------------- phase 2: agg_p = nf_p^T @ w3_p via MFMA ----------------
    // Zero-padded K: k = q (0..15 real, 16..31 zero). Per wave: its 4 points.
    {
        int wv = t >> 6, ln = t & 63;
        int nn = ln & 15, quad = ln >> 4;
        bool lo = quad < 2;
        int kr = (quad & 1) * 8;
        f32x4 acc2[4][2];
#pragma unroll
        for (int pp = 0; pp < 4; pp++) {
            int p2 = wv * 4 + pp;
            bf16x8 bfrag;
#pragma unroll
            for (int j = 0; j < 8; j++)
                bfrag[j] = lo ? U.a.w3b[p2][kr + j][nn] : (__bf16)0.f;
#pragma unroll
            for (int h = 0; h < 2; h++) {
                bf16x8 afrag;
#pragma unroll
                for (int j = 0; j < 8; j++)
                    afrag[j] = lo ? U.a.nfb[p2][kr + j][h * 16 + nn] : (__bf16)0.f;
                f32x4 z = {0.f, 0.f, 0.f, 0.f};
                acc2[pp][h] = __builtin_amdgcn_mfma_f32_16x16x32_bf16(afrag, bfrag, z, 0, 0, 0);
            }
        }
        __syncthreads();          // all union-a reads complete before overwrite
#pragma unroll
        for (int pp = 0; pp < 4; pp++) {
            int p2 = wv * 4 + pp;
#pragma unroll
            for (int h = 0; h < 2; h++)
#pragma unroll
                for (int r = 0; r < 4; r++)
                    U.aggB[p2][(h * 16 + quad * 4 + r) * 16 + nn] = (__bf16)acc2[pp][h][r];
        }
    }
    __syncthreads();

    // ---------------- phase 3: out64 = relu(agg @ wlin + blin), MFMA --------
    {
        int wv = t >> 6, ln = t & 63;
        int n = ln & 15, quad = ln >> 4;
        f32x4 acc = {0.f, 0.f, 0.f, 0.f};
        const __bf16* Bp = wlinT + ((wv * 16 + n) * 512 + quad * 8);
#pragma unroll
        for (int kk = 0; kk < 16; kk++) {
            bf16x8 a = *(const bf16x8*)(&U.aggB[n][kk * 32 + quad * 8]);
            bf16x8 b = *(const bf16x8*)(Bp + kk * 32);
            acc = __builtin_amdgcn_mfma_f32_16x16x32_bf16(a, b, acc, 0, 0, 0);
        }
        int col = wv * 16 + n;
        float bl = blin[col];
#pragma unroll
        for (int r = 0; r < 4; r++)
            sO[quad * 4 + r][col] = (__bf16)fmaxf(acc[r] + bl, 0.f);
    }
    __syncthreads();

    // ---------------- phase 4: out = leaky(out64@wu2 + sf@wsc + b), MFMA ----
    {
        int wv = t >> 6, ln = t & 63;
        int n = ln & 15, quad = ln >> 4;
        bf16x8 aO0 = *(const bf16x8*)(&sO[n][quad * 8]);
        bf16x8 aO1 = *(const bf16x8*)(&sO[n][32 + quad * 8]);
        bf16x8 aS0 = *(const bf16x8*)(&sS[n][quad * 8]);
        bf16x8 aS1 = *(const bf16x8*)(&sS[n][32 + quad * 8]);
        long mbase = (long)blockIdx.x * 16;
#pragma unroll
        for (int tt = 0; tt < 2; tt++) {
            int T = wv * 2 + tt;
            int col = T * 16 + n;
            const __bf16* B1 = wu2T + (col * 64 + quad * 8);
            const __bf16* B2 = wscT + (col * 64 + quad * 8);
            f32x4 acc = {0.f, 0.f, 0.f, 0.f};
            acc = __builtin_amdgcn_mfma_f32_16x16x32_bf16(aO0, *(const bf16x8*)(B1), acc, 0, 0, 0);
            acc = __builtin_amdgcn_mfma_f32_16x16x32_bf16(aO1, *(const bf16x8*)(B1 + 32), acc, 0, 0, 0);
            acc = __builtin_amdgcn_mfma_f32_16x16x32_bf16(aS0, *(const bf16x8*)(B2), acc, 0, 0, 0);
            acc = __builtin_amdgcn_mfma_f32_16x16x32_bf16(aS1, *(const bf16x8*)(B2 + 32), acc, 0, 0, 0);
            float bb = bu2[col] + bsc[col];
#pragma unroll
            for (int r = 0; r < 4; r++) {
                long mm = mbase + quad * 4 + r;
                if (mm < (long)M) {
                    float x = acc[r] + bb;
                    out[mm * 128 + col] = x > 0.f ? x : 0.1f * x;
                }
            }
        }
    }
}

extern "C" void kernel_launch(void* const* d_in, const int* in_sizes, int n_in,
                              void* d_out, int out_size, void* d_ws, size_t ws_size,
                              hipStream_t stream)
{
    const float* dense_feats = (const float*)d_in[1];
    const float* vi    = (const float*)d_in[5];
    const int*   nei   = (const int*)d_in[6];
    const float* w_u1  = (const float*)d_in[7];
    const float* b_u1  = (const float*)d_in[8];
    const float* w_gu  = (const float*)d_in[9];
    const float* b_gu  = (const float*)d_in[10];
    const float* w_pe  = (const float*)d_in[11];
    const float* b_pe  = (const float*)d_in[12];
    const float* w_g1  = (const float*)d_in[13];
    const float* b_g1  = (const float*)d_in[14];
    const float* w_g2  = (const float*)d_in[15];
    const float* b_g2  = (const float*)d_in[16];
    const float* w_wn1 = (const float*)d_in[17];
    const float* b_wn1 = (const float*)d_in[18];
    const float* w_wn2 = (const float*)d_in[19];
    const float* b_wn2 = (const float*)d_in[20];
    const float* w_wn3 = (const float*)d_in[21];
    const float* b_wn3 = (const float*)d_in[22];
    const float* w_lin = (const float*)d_in[23];
    const float* b_lin = (const float*)d_in[24];
    const float* w_u2  = (const float*)d_in[25];
    const float* b_u2  = (const float*)d_in[26];
    const float* w_sc  = (const float*)d_in[27];
    const float* b_sc  = (const float*)d_in[28];

    int N = in_sizes[1] / 64;     // 200000 (N % 64 == 0)
    int M = in_sizes[6] / 16;     // 100000 (M % 16 == 0)

    __bf16* fx    = (__bf16*)d_ws;                  // [N,32] bf16
    __bf16* gxp   = fx + (size_t)N * 32;            // [N,32] bf16
    __bf16* dfb   = gxp + (size_t)N * 32;           // [N,64] bf16
    __bf16* wlinT = dfb + (size_t)N * 64;           // [64,512]
    __bf16* wu2T  = wlinT + 64 * 512;               // [128,64]
    __bf16* wscT  = wu2T + 128 * 64;                // [128,64]

    prep_kernel<<<(64 * 512 + 2 * 128 * 64 + 255) / 256, 256, 0, stream>>>(
        w_lin, w_u2, w_sc, wlinT, wu2T, wscT);

    feats_kernel<<<N / 64, 256, 0, stream>>>(
        dense_feats, w_u1, b_u1, w_gu, b_gu, fx, gxp, dfb, N);

    pcf_kernel<<<(M + 15) / 16, 256, 0, stream>>>(
        vi, nei, dfb, fx, gxp,
        w_pe, b_pe, w_g1, b_g1, w_g2, b_g2,
        w_wn1, b_wn1, w_wn2, b_wn2, w_wn3, b_wn3,
        wlinT, b_lin, wu2T, b_u2, wscT, b_sc,
        (float*)d_out, M);
}